// Round 20
// baseline (77.028 us; speedup 1.0000x reference)
//
#include <hip/hip_runtime.h>

// RetinaNet matcher: gt_boxes [B=8, G=64, 4] f32, anchors [A=120000, 4] f32.
// Outputs (concat in d_out, f32): matched_idxs [B,A] (as float), matched_vals [B,A].
//
// Numerics: bit-exact vs np (absmax 0.0 R5-R19). opaque() barriers on every
// mul -> no FMA-contraction site. div_rn() = correctly-rounded divide for
// mid-range operands. argmax tie-break = first g (strict >). IoU >= 0 ->
// uint atomicMax bit-exact.
//
// R20: R19's pass1 was scatter-write bound (WRITE 66MB vs 11.5 useful, 8x
// line amplification). Invert the permutation: pass1/k_patch write SORTED-
// order arrays (coalesced); new k_emit gathers via inv[a] (random READS,
// L2-absorbed; 15.4MB working set) and writes original-order outputs
// coalesced. k_scat emits inv[a]=pos (coalesced); orig dropped.
// Sort chain, skip logic, E-factorization, all IoU ops byte-identical to
// the proven path. inv is a bijection -> every output written exactly once.

static constexpr int G = 64;
static constexpr int NCELL = 256;   // 16x16 grid of 50px cells

__device__ __forceinline__ float opaque(float x) {
    asm volatile("" : "+v"(x));  // no-op; blocks FMA contraction across x
    return x;
}

__device__ __forceinline__ int vindex(int i) {
    asm volatile("" : "+v"(i));  // force VGPR residency; defeats scalarization
    return i;
}

__device__ __forceinline__ float box_area(float x1, float y1, float x2, float y2) {
    return opaque(__fmul_rn(__fsub_rn(x2, x1), __fsub_rn(y2, y1)));
}

__device__ __forceinline__ float inter_area(float gx1, float gy1, float gx2, float gy2,
                                            float ax1, float ay1, float ax2, float ay2) {
    float ltx = fmaxf(gx1, ax1);
    float lty = fmaxf(gy1, ay1);
    float rbx = fminf(gx2, ax2);
    float rby = fminf(gy2, ay2);
    float w = fmaxf(__fsub_rn(rbx, ltx), 0.0f);
    float h = fmaxf(__fsub_rn(rby, lty), 0.0f);
    return opaque(__fmul_rn(w, h));
}

// Correctly-rounded f32 divide for mid-range operands (no denormal/overflow).
__device__ __forceinline__ float div_rn(float n, float d) {
    float r = __builtin_amdgcn_rcpf(d);
    float e = fmaf(-d, r, 1.0f);
    r = fmaf(e, r, r);
    float q = __fmul_rn(n, r);
    float s = fmaf(-d, q, n);
    q = fmaf(s, r, q);
    s = fmaf(-d, q, n);
    q = fmaf(s, r, q);
    return q;
}

#define DPP_MAX_STAGE(x, ctrl)                                                   \
    do {                                                                         \
        int _yi = __builtin_amdgcn_update_dpp(__float_as_int(x),                 \
                                              __float_as_int(x), (ctrl),         \
                                              0xf, 0xf, false);                  \
        (x) = fmaxf((x), __int_as_float(_yi));                                   \
    } while (0)

#define DPP_MIN_STAGE(x, ctrl)                                                   \
    do {                                                                         \
        int _yi = __builtin_amdgcn_update_dpp(__float_as_int(x),                 \
                                              __float_as_int(x), (ctrl),         \
                                              0xf, 0xf, false);                  \
        (x) = fminf((x), __int_as_float(_yi));                                   \
    } while (0)

// Full wave64 max; result valid in lane 63.
__device__ __forceinline__ float wave_max_lane63(float x) {
    DPP_MAX_STAGE(x, 0xB1);   // quad_perm xor1
    DPP_MAX_STAGE(x, 0x4E);   // quad_perm xor2
    DPP_MAX_STAGE(x, 0x141);  // row_half_mirror
    DPP_MAX_STAGE(x, 0x140);  // row_mirror
    DPP_MAX_STAGE(x, 0x142);  // row_bcast15
    DPP_MAX_STAGE(x, 0x143);  // row_bcast31
    return x;
}

__device__ __forceinline__ float wave_min_lane63(float x) {
    DPP_MIN_STAGE(x, 0xB1);
    DPP_MIN_STAGE(x, 0x4E);
    DPP_MIN_STAGE(x, 0x141);
    DPP_MIN_STAGE(x, 0x140);
    DPP_MIN_STAGE(x, 0x142);
    DPP_MIN_STAGE(x, 0x143);
    return x;
}

__device__ __forceinline__ float lane63_bcast(float x) {
    return __int_as_float(__builtin_amdgcn_readlane(__float_as_int(x), 63));
}

__device__ __forceinline__ int cell_of(float4 ab) {
    float cx = (ab.x + ab.z) * 0.5f;   // binning only; precision irrelevant
    float cy = (ab.y + ab.w) * 0.5f;
    int cxi = (int)(cx * 0.02f); cxi = cxi < 0 ? 0 : (cxi > 15 ? 15 : cxi);
    int cyi = (int)(cy * 0.02f); cyi = cyi < 0 ? 0 : (cyi > 15 ? 15 : cyi);
    return cyi * 16 + cxi;
}

// Sort step 1 (+init): per-block LDS hist -> bh[c*NB+blk]; blocks 0,1 also
// zero hpg and fill gab (BG = 512 <= 2*256).
__global__ void k_count(const float* __restrict__ gt,
                        const float* __restrict__ anchors,
                        unsigned int* __restrict__ bh,
                        unsigned int* __restrict__ hpg,
                        float* __restrict__ gab,
                        int A, int NB, int BG) {
    int t = threadIdx.x;
    int gi = blockIdx.x * 256 + t;
    if (gi < BG) {                      // init (blocks 0..1 only)
        hpg[gi] = 0u;
        float4 gb = ((const float4*)gt)[gi];
        gab[gi] = box_area(gb.x, gb.y, gb.z, gb.w);
    }
    __shared__ unsigned int h[NCELL];
    h[t] = 0u;
    __syncthreads();
    int a = blockIdx.x * 256 + t;
    if (a < A) atomicAdd(&h[cell_of(((const float4*)anchors)[a])], 1u);
    __syncthreads();
    bh[(size_t)t * NB + blockIdx.x] = h[t];   // row t = cell t
}

// Sort step 2: 256 independent blocks; block c exclusive-scans row c of bh.
__global__ void k_rowscan(unsigned int* __restrict__ bh,
                          unsigned int* __restrict__ cellTot, int NB) {
    const int c = blockIdx.x;
    unsigned int* row = bh + (size_t)c * NB;
    __shared__ unsigned int s[256];
    __shared__ unsigned int carry;
    if (threadIdx.x == 0) carry = 0u;
    __syncthreads();
    for (int base = 0; base < NB; base += 256) {
        int i = base + threadIdx.x;
        unsigned int v = (i < NB) ? row[i] : 0u;
        s[threadIdx.x] = v;
        __syncthreads();
        for (int d = 1; d < 256; d <<= 1) {
            unsigned int add = (threadIdx.x >= d) ? s[threadIdx.x - d] : 0u;
            __syncthreads();
            s[threadIdx.x] += add;
            __syncthreads();
        }
        unsigned int excl = s[threadIdx.x] - v + carry;   // uses OLD carry
        if (i < NB) row[i] = excl;
        __syncthreads();
        if (threadIdx.x == 255) carry += s[255];
        __syncthreads();
    }
    if (threadIdx.x == 0) cellTot[c] = carry;
}

// Sort step 3 (+base): scatter anchors to sorted order; emit inv[a]=pos
// (coalesced by a). cellBase from in-block LDS scan of cellTot.
__global__ void k_scat(const float* __restrict__ anchors,
                       const unsigned int* __restrict__ bh,
                       const unsigned int* __restrict__ cellTot,
                       float* __restrict__ sortedA,
                       int* __restrict__ inv, int A, int NB) {
    __shared__ unsigned int cb[NCELL];   // inclusive scan of cellTot
    __shared__ unsigned int tot[NCELL];
    __shared__ unsigned int h[NCELL];
    int t = threadIdx.x;
    unsigned int v = cellTot[t];
    cb[t] = v;
    tot[t] = v;
    h[t] = 0u;
    __syncthreads();
    for (int d = 1; d < NCELL; d <<= 1) {
        unsigned int add = (t >= d) ? cb[t - d] : 0u;
        __syncthreads();
        cb[t] += add;
        __syncthreads();
    }
    int a = blockIdx.x * 256 + t;
    if (a < A) {
        float4 ab = ((const float4*)anchors)[a];
        int c = cell_of(ab);
        unsigned int lr = atomicAdd(&h[c], 1u);          // LDS only
        unsigned int base = cb[c] - tot[c];              // exclusive cellBase
        unsigned int pos = base + bh[(size_t)c * NB + blockIdx.x] + lr;
        ((float4*)sortedA)[pos] = ab;
        inv[a] = (int)pos;                               // coalesced by a
    }
}

// Pass 1: 4 anchors/thread, g-outer, wave-bbox pre-skip + inner ballot skip,
// DPP wave max, LDS block max. Writes tentative outputs + amax in SORTED
// order (coalesced), plus sred dump. Grid: (nchunks = ceil(A/1024), B).
__global__ __launch_bounds__(256, 4)
void pass1_k(const float* __restrict__ gt,
             const float* __restrict__ anchors,
             const float* __restrict__ gab,
             unsigned int* __restrict__ hpg,
             unsigned int* __restrict__ sredg,
             float* __restrict__ outi_s,
             float* __restrict__ outv_s,
             int* __restrict__ amaxS,
             int A, int nchunks) {
    const int b = blockIdx.y;
    const int t = threadIdx.x;

    __shared__ unsigned int sred[G];
    if (t < G) sred[t] = 0u;
    __syncthreads();

    const int base = blockIdx.x * 1024;
    float ax1[4], ay1[4], ax2[4], ay2[4], aar[4];
    bool val[4];
#pragma unroll
    for (int k = 0; k < 4; ++k) {
        int a = base + k * 256 + t;
        val[k] = (a < A);
        float4 ab = ((const float4*)anchors)[val[k] ? a : 0];
        ax1[k] = val[k] ? ab.x : 3.0e38f;    // invalid: x1>x2 -> inter==+0
        ay1[k] = val[k] ? ab.y : 3.0e38f;
        ax2[k] = val[k] ? ab.z : -3.0e38f;
        ay2[k] = val[k] ? ab.w : -3.0e38f;
        aar[k] = val[k] ? box_area(ax1[k], ay1[k], ax2[k], ay2[k]) : 0.0f;
    }
    // invalid lanes: inter=0, aar=0 -> q = +0.0 exactly; never affects maxes.

    float wx1 = fminf(fminf(ax1[0], ax1[1]), fminf(ax1[2], ax1[3]));
    float wy1 = fminf(fminf(ay1[0], ay1[1]), fminf(ay1[2], ay1[3]));
    float wx2 = fmaxf(fmaxf(ax2[0], ax2[1]), fmaxf(ax2[2], ax2[3]));
    float wy2 = fmaxf(fmaxf(ay2[0], ay2[1]), fmaxf(ay2[2], ay2[3]));
    wx1 = lane63_bcast(wave_min_lane63(wx1));
    wy1 = lane63_bcast(wave_min_lane63(wy1));
    wx2 = lane63_bcast(wave_max_lane63(wx2));
    wy2 = lane63_bcast(wave_max_lane63(wy2));

    const float4* gtb = (const float4*)gt + (size_t)b * G;
    const float* gas = gab + b * G;

    float vmax[4] = {0.0f, 0.0f, 0.0f, 0.0f};
    int amax[4] = {0, 0, 0, 0};

#pragma unroll 4
    for (int g = 0; g < G; ++g) {
        const int gv = vindex(g);              // VMEM broadcast (L1-hot)
        const float4 gb = gtb[gv];
        float tlx = fmaxf(gb.x, wx1), trx = fminf(gb.z, wx2);
        float tly = fmaxf(gb.y, wy1), tby = fminf(gb.w, wy2);
        if ((trx > tlx) && (tby > tly)) {      // wave-uniform bbox test
            float inter[4];
#pragma unroll
            for (int k = 0; k < 4; ++k)
                inter[k] = inter_area(gb.x, gb.y, gb.z, gb.w,
                                      ax1[k], ay1[k], ax2[k], ay2[k]);
            float itest = fmaxf(fmaxf(inter[0], inter[1]),
                                fmaxf(inter[2], inter[3]));
            if (__any(itest > 0.0f)) {
                const float ga = gas[gv];
                float m = 0.0f;
#pragma unroll
                for (int k = 0; k < 4; ++k) {
                    float denom = __fsub_rn(__fadd_rn(ga, aar[k]), inter[k]);
                    float q = div_rn(inter[k], denom);
                    if (q > vmax[k]) { vmax[k] = q; amax[k] = g; }  // first-max
                    m = fmaxf(m, q);
                }
                m = wave_max_lane63(m);
                if ((t & 63) == 63)
                    atomicMax(&sred[g], __float_as_uint(m));
            }
        }
    }

#pragma unroll
    for (int k = 0; k < 4; ++k) {
        if (!val[k]) continue;
        int a = base + k * 256 + t;
        size_t sidx = (size_t)b * A + a;       // SORTED order: coalesced
        amaxS[sidx] = amax[k];
        int mt;                                // tentative: pu assumed false
        if (vmax[k] < 0.4f) mt = -1;
        else if (vmax[k] < 0.5f) mt = -2;
        else mt = amax[k];
        outi_s[sidx] = (float)mt;
        outv_s[sidx] = vmax[k];
    }

    __syncthreads();
    if (t < G) {
        atomicMax(&hpg[b * G + t], sred[t]);
        sredg[(size_t)(b * nchunks + blockIdx.x) * G + t] = sred[t];
    }
}

// Patch: E[g] = (sred_blk[g]==hpg[g]); exit if E==0 (common). Else recompute
// q for E-set g's (bit-exact) and overwrite outi_s=amaxS where pu. Coalesced.
__global__ __launch_bounds__(256, 8)
void k_patch(const float* __restrict__ gt,
             const float* __restrict__ anchors,
             const float* __restrict__ gab,
             const unsigned int* __restrict__ hpg,
             const unsigned int* __restrict__ sredg,
             const int* __restrict__ amaxS,
             float* __restrict__ outi_s,
             int A, int nchunks) {
    const int b = blockIdx.y;
    const int t = threadIdx.x;
    const int base = blockIdx.x * 1024;

    const unsigned int* sb = sredg + (size_t)(b * nchunks + blockIdx.x) * G;
    const unsigned int* hb = hpg + b * G;

    unsigned long long E = 0ull;
#pragma unroll 16
    for (int g = 0; g < G; ++g)
        E |= (sb[g] == hb[g]) ? (1ull << g) : 0ull;
    if (E == 0ull) return;              // common fast exit (block-uniform)

    const float4* gtb = (const float4*)gt + (size_t)b * G;
    const float* gas = gab + b * G;
    float ax1[4], ay1[4], ax2[4], ay2[4], aar[4];
    bool val[4];
#pragma unroll
    for (int k = 0; k < 4; ++k) {
        int a = base + k * 256 + t;
        val[k] = (a < A);
        float4 ab = ((const float4*)anchors)[val[k] ? a : 0];
        ax1[k] = val[k] ? ab.x : 3.0e38f;
        ay1[k] = val[k] ? ab.y : 3.0e38f;
        ax2[k] = val[k] ? ab.z : -3.0e38f;
        ay2[k] = val[k] ? ab.w : -3.0e38f;
        aar[k] = val[k] ? box_area(ax1[k], ay1[k], ax2[k], ay2[k]) : 0.0f;
    }

    bool pu[4] = {false, false, false, false};
    unsigned long long e = E;
    while (e) {
        int g = __builtin_ctzll(e);
        e &= e - 1;
        float4 gb = gtb[g];
        float ga = gas[g];
        float hgf = __uint_as_float(hb[g]);
#pragma unroll
        for (int k = 0; k < 4; ++k) {
            float inter = inter_area(gb.x, gb.y, gb.z, gb.w,
                                     ax1[k], ay1[k], ax2[k], ay2[k]);
            float denom = __fsub_rn(__fadd_rn(ga, aar[k]), inter);
            float q = div_rn(inter, denom);
            pu[k] = pu[k] | (q == hgf);
        }
    }

#pragma unroll
    for (int k = 0; k < 4; ++k) {
        int a = base + k * 256 + t;
        if (!val[k] || !pu[k]) continue;
        size_t sidx = (size_t)b * A + a;
        outi_s[sidx] = (float)amaxS[sidx];     // coalesced overwrite
    }
}

// Emit: original-order outputs via gather. Coalesced writes; random reads
// (L2-resident 15.4MB). inv==nullptr -> identity (fallback).
__global__ __launch_bounds__(256, 8)
void k_emit(const float* __restrict__ outi_s,
            const float* __restrict__ outv_s,
            const int* __restrict__ inv,
            float* __restrict__ out_idx,
            float* __restrict__ out_val,
            int A) {
    const int b = blockIdx.y;
    const int base = blockIdx.x * 1024;
#pragma unroll
    for (int k = 0; k < 4; ++k) {
        int a = base + k * 256 + threadIdx.x;
        if (a >= A) continue;
        int p = inv ? inv[a] : a;              // coalesced read
        size_t si = (size_t)b * A + p;         // gather
        size_t oi = (size_t)b * A + a;         // coalesced write
        out_idx[oi] = outi_s[si];
        out_val[oi] = outv_s[si];
    }
}

extern "C" void kernel_launch(void* const* d_in, const int* in_sizes, int n_in,
                              void* d_out, int out_size, void* d_ws, size_t ws_size,
                              hipStream_t stream) {
    const float* gt = (const float*)d_in[0];
    const float* anchors = (const float*)d_in[1];
    const int BG = in_sizes[0] / 4;   // B*G = 512
    const int B = BG / G;             // 8
    const int A = in_sizes[1] / 4;    // 120000

    const int nchunks = (A + 1023) / 1024;
    const int NB = (A + 255) / 256;   // sort-kernel blocks

    // ws layout (u32 units):
    // [0,512) hpg | [512,1024) gab | [1024,1280) cellTot |
    // [1280, +NB*256) bh | (align4) sortedA 4A | inv A |
    // sredg nchunks*B*64 | outi_s B*A | outv_s B*A | amaxS B*A
    unsigned int* ws = (unsigned int*)d_ws;
    unsigned int* hpg = ws;
    float* gab = (float*)(ws + 512);
    unsigned int* cellTot = ws + 1024;
    unsigned int* bh = ws + 1280;
    size_t soff = 1280 + (size_t)NB * 256;
    soff = (soff + 3) & ~(size_t)3;                 // 16B align for float4
    float* sortedA = (float*)(ws + soff);
    int* inv = (int*)(ws + soff + 4 * (size_t)A);
    unsigned int* sredg = ws + soff + 5 * (size_t)A;
    size_t ooff = soff + 5 * (size_t)A + (size_t)nchunks * B * G;
    float* outi_s = (float*)(ws + ooff);
    float* outv_s = outi_s + (size_t)B * A;
    int* amaxS = (int*)(outv_s + (size_t)B * A);
    const size_t need = (ooff + 3 * (size_t)B * A) * 4;
    const bool sorted = (ws_size >= need);

    float* out_idx = (float*)d_out;
    float* out_val = out_idx + (size_t)B * A;

    dim3 g1(nchunks, B);
    if (sorted) {
        k_count<<<NB, 256, 0, stream>>>(gt, anchors, bh, hpg, gab, A, NB, BG);
        k_rowscan<<<NCELL, 256, 0, stream>>>(bh, cellTot, NB);
        k_scat<<<NB, 256, 0, stream>>>(anchors, bh, cellTot, sortedA, inv, A, NB);
        pass1_k<<<g1, 256, 0, stream>>>(gt, sortedA, gab, hpg, sredg,
                                        outi_s, outv_s, amaxS, A, nchunks);
        k_patch<<<g1, 256, 0, stream>>>(gt, sortedA, gab, hpg, sredg,
                                        amaxS, outi_s, A, nchunks);
        k_emit<<<g1, 256, 0, stream>>>(outi_s, outv_s, inv,
                                       out_idx, out_val, A);
    } else {
        // Fallback: unsorted identity order (no sort kernels, inv=nullptr).
        k_count<<<NB, 256, 0, stream>>>(gt, anchors, bh, hpg, gab, A, NB, BG);
        pass1_k<<<g1, 256, 0, stream>>>(gt, anchors, gab, hpg, sredg,
                                        outi_s, outv_s, amaxS, A, nchunks);
        k_patch<<<g1, 256, 0, stream>>>(gt, anchors, gab, hpg, sredg,
                                        amaxS, outi_s, A, nchunks);
        k_emit<<<g1, 256, 0, stream>>>(outi_s, outv_s, nullptr,
                                       out_idx, out_val, A);
    }
}

// Round 21
// 67.807 us; speedup vs baseline: 1.1360x; 1.1360x over previous
//
#include <hip/hip_runtime.h>

// RetinaNet matcher: gt_boxes [B=8, G=64, 4] f32, anchors [A=120000, 4] f32.
// Outputs (concat in d_out, f32): matched_idxs [B,A] (as float), matched_vals [B,A].
//
// Numerics: bit-exact vs np (absmax 0.0 R5-R20). opaque() barriers on every
// mul -> no FMA-contraction site. div_rn() = correctly-rounded divide for
// mid-range operands. argmax tie-break = first g (strict >). IoU >= 0 ->
// uint atomicMax bit-exact.
//
// R21 = R19 (best, 68.3us) with the scatter halved. R19 pass1 did TWO
// scattered 4B stores per anchor (out_idx + out_val, different lines) ->
// 66MB write sectors. R20 proved gathers are worse than scatters. So:
// ONE scattered float2 store per anchor into outiv[b*A+orig[a]] (~31MB
// sectors), then k_emit de-interleaves coalesced (read 7.7 + write 7.7MB
// streaming). k_patch overwrites outiv.x (rare). orig is a bijection ->
// every outiv entry written once per call; deterministic replay.

static constexpr int G = 64;
static constexpr int NCELL = 256;   // 16x16 grid of 50px cells

__device__ __forceinline__ float opaque(float x) {
    asm volatile("" : "+v"(x));  // no-op; blocks FMA contraction across x
    return x;
}

__device__ __forceinline__ int vindex(int i) {
    asm volatile("" : "+v"(i));  // force VGPR residency; defeats scalarization
    return i;
}

__device__ __forceinline__ float box_area(float x1, float y1, float x2, float y2) {
    return opaque(__fmul_rn(__fsub_rn(x2, x1), __fsub_rn(y2, y1)));
}

__device__ __forceinline__ float inter_area(float gx1, float gy1, float gx2, float gy2,
                                            float ax1, float ay1, float ax2, float ay2) {
    float ltx = fmaxf(gx1, ax1);
    float lty = fmaxf(gy1, ay1);
    float rbx = fminf(gx2, ax2);
    float rby = fminf(gy2, ay2);
    float w = fmaxf(__fsub_rn(rbx, ltx), 0.0f);
    float h = fmaxf(__fsub_rn(rby, lty), 0.0f);
    return opaque(__fmul_rn(w, h));
}

// Correctly-rounded f32 divide for mid-range operands (no denormal/overflow).
__device__ __forceinline__ float div_rn(float n, float d) {
    float r = __builtin_amdgcn_rcpf(d);
    float e = fmaf(-d, r, 1.0f);
    r = fmaf(e, r, r);
    float q = __fmul_rn(n, r);
    float s = fmaf(-d, q, n);
    q = fmaf(s, r, q);
    s = fmaf(-d, q, n);
    q = fmaf(s, r, q);
    return q;
}

#define DPP_MAX_STAGE(x, ctrl)                                                   \
    do {                                                                         \
        int _yi = __builtin_amdgcn_update_dpp(__float_as_int(x),                 \
                                              __float_as_int(x), (ctrl),         \
                                              0xf, 0xf, false);                  \
        (x) = fmaxf((x), __int_as_float(_yi));                                   \
    } while (0)

#define DPP_MIN_STAGE(x, ctrl)                                                   \
    do {                                                                         \
        int _yi = __builtin_amdgcn_update_dpp(__float_as_int(x),                 \
                                              __float_as_int(x), (ctrl),         \
                                              0xf, 0xf, false);                  \
        (x) = fminf((x), __int_as_float(_yi));                                   \
    } while (0)

// Full wave64 max; result valid in lane 63.
__device__ __forceinline__ float wave_max_lane63(float x) {
    DPP_MAX_STAGE(x, 0xB1);   // quad_perm xor1
    DPP_MAX_STAGE(x, 0x4E);   // quad_perm xor2
    DPP_MAX_STAGE(x, 0x141);  // row_half_mirror
    DPP_MAX_STAGE(x, 0x140);  // row_mirror
    DPP_MAX_STAGE(x, 0x142);  // row_bcast15
    DPP_MAX_STAGE(x, 0x143);  // row_bcast31
    return x;
}

__device__ __forceinline__ float wave_min_lane63(float x) {
    DPP_MIN_STAGE(x, 0xB1);
    DPP_MIN_STAGE(x, 0x4E);
    DPP_MIN_STAGE(x, 0x141);
    DPP_MIN_STAGE(x, 0x140);
    DPP_MIN_STAGE(x, 0x142);
    DPP_MIN_STAGE(x, 0x143);
    return x;
}

__device__ __forceinline__ float lane63_bcast(float x) {
    return __int_as_float(__builtin_amdgcn_readlane(__float_as_int(x), 63));
}

__device__ __forceinline__ int cell_of(float4 ab) {
    float cx = (ab.x + ab.z) * 0.5f;   // binning only; precision irrelevant
    float cy = (ab.y + ab.w) * 0.5f;
    int cxi = (int)(cx * 0.02f); cxi = cxi < 0 ? 0 : (cxi > 15 ? 15 : cxi);
    int cyi = (int)(cy * 0.02f); cyi = cyi < 0 ? 0 : (cyi > 15 ? 15 : cyi);
    return cyi * 16 + cxi;
}

// Sort step 1 (+init): per-block LDS hist -> bh[c*NB+blk]; blocks 0,1 also
// zero hpg and fill gab (BG = 512 <= 2*256).
__global__ void k_count(const float* __restrict__ gt,
                        const float* __restrict__ anchors,
                        unsigned int* __restrict__ bh,
                        unsigned int* __restrict__ hpg,
                        float* __restrict__ gab,
                        int A, int NB, int BG) {
    int t = threadIdx.x;
    int gi = blockIdx.x * 256 + t;
    if (gi < BG) {                      // init (blocks 0..1 only)
        hpg[gi] = 0u;
        float4 gb = ((const float4*)gt)[gi];
        gab[gi] = box_area(gb.x, gb.y, gb.z, gb.w);
    }
    __shared__ unsigned int h[NCELL];
    h[t] = 0u;
    __syncthreads();
    int a = blockIdx.x * 256 + t;
    if (a < A) atomicAdd(&h[cell_of(((const float4*)anchors)[a])], 1u);
    __syncthreads();
    bh[(size_t)t * NB + blockIdx.x] = h[t];   // row t = cell t
}

// Sort step 2: 256 independent blocks; block c exclusive-scans row c of bh.
__global__ void k_rowscan(unsigned int* __restrict__ bh,
                          unsigned int* __restrict__ cellTot, int NB) {
    const int c = blockIdx.x;
    unsigned int* row = bh + (size_t)c * NB;
    __shared__ unsigned int s[256];
    __shared__ unsigned int carry;
    if (threadIdx.x == 0) carry = 0u;
    __syncthreads();
    for (int base = 0; base < NB; base += 256) {
        int i = base + threadIdx.x;
        unsigned int v = (i < NB) ? row[i] : 0u;
        s[threadIdx.x] = v;
        __syncthreads();
        for (int d = 1; d < 256; d <<= 1) {
            unsigned int add = (threadIdx.x >= d) ? s[threadIdx.x - d] : 0u;
            __syncthreads();
            s[threadIdx.x] += add;
            __syncthreads();
        }
        unsigned int excl = s[threadIdx.x] - v + carry;   // uses OLD carry
        if (i < NB) row[i] = excl;
        __syncthreads();
        if (threadIdx.x == 255) carry += s[255];
        __syncthreads();
    }
    if (threadIdx.x == 0) cellTot[c] = carry;
}

// Sort step 3 (+base): scatter anchors to sorted order + orig[pos]=a.
// cellBase from in-block LDS scan of cellTot.
__global__ void k_scat(const float* __restrict__ anchors,
                       const unsigned int* __restrict__ bh,
                       const unsigned int* __restrict__ cellTot,
                       float* __restrict__ sortedA,
                       int* __restrict__ orig, int A, int NB) {
    __shared__ unsigned int cb[NCELL];   // inclusive scan of cellTot
    __shared__ unsigned int tot[NCELL];
    __shared__ unsigned int h[NCELL];
    int t = threadIdx.x;
    unsigned int v = cellTot[t];
    cb[t] = v;
    tot[t] = v;
    h[t] = 0u;
    __syncthreads();
    for (int d = 1; d < NCELL; d <<= 1) {
        unsigned int add = (t >= d) ? cb[t - d] : 0u;
        __syncthreads();
        cb[t] += add;
        __syncthreads();
    }
    int a = blockIdx.x * 256 + t;
    if (a < A) {
        float4 ab = ((const float4*)anchors)[a];
        int c = cell_of(ab);
        unsigned int lr = atomicAdd(&h[c], 1u);          // LDS only
        unsigned int base = cb[c] - tot[c];              // exclusive cellBase
        unsigned int pos = base + bh[(size_t)c * NB + blockIdx.x] + lr;
        ((float4*)sortedA)[pos] = ab;
        orig[pos] = a;
    }
}

// Pass 1: 4 anchors/thread, g-outer, wave-bbox pre-skip + inner ballot skip,
// DPP wave max, LDS block max. Writes ONE scattered float2 (idx,val) per
// anchor via orig, amaxS coalesced (sorted order), sred dump.
// Grid: (nchunks = ceil(A/1024), B), block 256.
template <bool SCATTER>
__global__ __launch_bounds__(256, 4)
void pass1_k(const float* __restrict__ gt,
             const float* __restrict__ anchors,
             const float* __restrict__ gab,
             unsigned int* __restrict__ hpg,
             unsigned int* __restrict__ sredg,
             int* __restrict__ amaxS,
             const int* __restrict__ orig,
             float2* __restrict__ outiv,
             int A, int nchunks) {
    const int b = blockIdx.y;
    const int t = threadIdx.x;

    __shared__ unsigned int sred[G];
    if (t < G) sred[t] = 0u;
    __syncthreads();

    const int base = blockIdx.x * 1024;
    float ax1[4], ay1[4], ax2[4], ay2[4], aar[4];
    bool val[4];
#pragma unroll
    for (int k = 0; k < 4; ++k) {
        int a = base + k * 256 + t;
        val[k] = (a < A);
        float4 ab = ((const float4*)anchors)[val[k] ? a : 0];
        ax1[k] = val[k] ? ab.x : 3.0e38f;    // invalid: x1>x2 -> inter==+0
        ay1[k] = val[k] ? ab.y : 3.0e38f;
        ax2[k] = val[k] ? ab.z : -3.0e38f;
        ay2[k] = val[k] ? ab.w : -3.0e38f;
        aar[k] = val[k] ? box_area(ax1[k], ay1[k], ax2[k], ay2[k]) : 0.0f;
    }
    // invalid lanes: inter=0, aar=0 -> q = +0.0 exactly; never affects maxes.

    float wx1 = fminf(fminf(ax1[0], ax1[1]), fminf(ax1[2], ax1[3]));
    float wy1 = fminf(fminf(ay1[0], ay1[1]), fminf(ay1[2], ay1[3]));
    float wx2 = fmaxf(fmaxf(ax2[0], ax2[1]), fmaxf(ax2[2], ax2[3]));
    float wy2 = fmaxf(fmaxf(ay2[0], ay2[1]), fmaxf(ay2[2], ay2[3]));
    wx1 = lane63_bcast(wave_min_lane63(wx1));
    wy1 = lane63_bcast(wave_min_lane63(wy1));
    wx2 = lane63_bcast(wave_max_lane63(wx2));
    wy2 = lane63_bcast(wave_max_lane63(wy2));

    const float4* gtb = (const float4*)gt + (size_t)b * G;
    const float* gas = gab + b * G;

    float vmax[4] = {0.0f, 0.0f, 0.0f, 0.0f};
    int amax[4] = {0, 0, 0, 0};

#pragma unroll 4
    for (int g = 0; g < G; ++g) {
        const int gv = vindex(g);              // VMEM broadcast (L1-hot)
        const float4 gb = gtb[gv];
        float tlx = fmaxf(gb.x, wx1), trx = fminf(gb.z, wx2);
        float tly = fmaxf(gb.y, wy1), tby = fminf(gb.w, wy2);
        if ((trx > tlx) && (tby > tly)) {      // wave-uniform bbox test
            float inter[4];
#pragma unroll
            for (int k = 0; k < 4; ++k)
                inter[k] = inter_area(gb.x, gb.y, gb.z, gb.w,
                                      ax1[k], ay1[k], ax2[k], ay2[k]);
            float itest = fmaxf(fmaxf(inter[0], inter[1]),
                                fmaxf(inter[2], inter[3]));
            if (__any(itest > 0.0f)) {
                const float ga = gas[gv];
                float m = 0.0f;
#pragma unroll
                for (int k = 0; k < 4; ++k) {
                    float denom = __fsub_rn(__fadd_rn(ga, aar[k]), inter[k]);
                    float q = div_rn(inter[k], denom);
                    if (q > vmax[k]) { vmax[k] = q; amax[k] = g; }  // first-max
                    m = fmaxf(m, q);
                }
                m = wave_max_lane63(m);
                if ((t & 63) == 63)
                    atomicMax(&sred[g], __float_as_uint(m));
            }
        }
    }

#pragma unroll
    for (int k = 0; k < 4; ++k) {
        if (!val[k]) continue;
        int a = base + k * 256 + t;
        size_t sidx = (size_t)b * A + a;       // sorted order: coalesced
        amaxS[sidx] = amax[k];
        int mt;                                // tentative: pu assumed false
        if (vmax[k] < 0.4f) mt = -1;
        else if (vmax[k] < 0.5f) mt = -2;
        else mt = amax[k];
        int ao = SCATTER ? orig[a] : a;
        outiv[(size_t)b * A + ao] = make_float2((float)mt, vmax[k]);  // 1 store
    }

    __syncthreads();
    if (t < G) {
        atomicMax(&hpg[b * G + t], sred[t]);
        sredg[(size_t)(b * nchunks + blockIdx.x) * G + t] = sred[t];
    }
}

// Patch: E[g] = (sred_blk[g]==hpg[g]); exit if E==0 (common). Else recompute
// q for E-set g's (bit-exact) and overwrite outiv.x = amax where pu.
template <bool SCATTER>
__global__ __launch_bounds__(256, 8)
void k_patch(const float* __restrict__ gt,
             const float* __restrict__ anchors,
             const float* __restrict__ gab,
             const unsigned int* __restrict__ hpg,
             const unsigned int* __restrict__ sredg,
             const int* __restrict__ amaxS,
             const int* __restrict__ orig,
             float2* __restrict__ outiv,
             int A, int nchunks) {
    const int b = blockIdx.y;
    const int t = threadIdx.x;
    const int base = blockIdx.x * 1024;

    const unsigned int* sb = sredg + (size_t)(b * nchunks + blockIdx.x) * G;
    const unsigned int* hb = hpg + b * G;

    unsigned long long E = 0ull;
#pragma unroll 16
    for (int g = 0; g < G; ++g)
        E |= (sb[g] == hb[g]) ? (1ull << g) : 0ull;
    if (E == 0ull) return;              // common fast exit (block-uniform)

    const float4* gtb = (const float4*)gt + (size_t)b * G;
    const float* gas = gab + b * G;
    float ax1[4], ay1[4], ax2[4], ay2[4], aar[4];
    bool val[4];
#pragma unroll
    for (int k = 0; k < 4; ++k) {
        int a = base + k * 256 + t;
        val[k] = (a < A);
        float4 ab = ((const float4*)anchors)[val[k] ? a : 0];
        ax1[k] = val[k] ? ab.x : 3.0e38f;
        ay1[k] = val[k] ? ab.y : 3.0e38f;
        ax2[k] = val[k] ? ab.z : -3.0e38f;
        ay2[k] = val[k] ? ab.w : -3.0e38f;
        aar[k] = val[k] ? box_area(ax1[k], ay1[k], ax2[k], ay2[k]) : 0.0f;
    }

    bool pu[4] = {false, false, false, false};
    unsigned long long e = E;
    while (e) {
        int g = __builtin_ctzll(e);
        e &= e - 1;
        float4 gb = gtb[g];
        float ga = gas[g];
        float hgf = __uint_as_float(hb[g]);
#pragma unroll
        for (int k = 0; k < 4; ++k) {
            float inter = inter_area(gb.x, gb.y, gb.z, gb.w,
                                     ax1[k], ay1[k], ax2[k], ay2[k]);
            float denom = __fsub_rn(__fadd_rn(ga, aar[k]), inter);
            float q = div_rn(inter, denom);
            pu[k] = pu[k] | (q == hgf);
        }
    }

#pragma unroll
    for (int k = 0; k < 4; ++k) {
        int a = base + k * 256 + t;
        if (!val[k] || !pu[k]) continue;
        int ao = SCATTER ? orig[a] : a;
        outiv[(size_t)b * A + ao].x = (float)amaxS[(size_t)b * A + a];
    }
}

// Emit: de-interleave outiv into the two output arrays. Fully coalesced.
__global__ __launch_bounds__(256, 8)
void k_emit(const float2* __restrict__ outiv,
            float* __restrict__ out_idx,
            float* __restrict__ out_val,
            int A) {
    const int b = blockIdx.y;
    const int base = blockIdx.x * 1024;
#pragma unroll
    for (int k = 0; k < 4; ++k) {
        int a = base + k * 256 + threadIdx.x;
        if (a >= A) continue;
        size_t i = (size_t)b * A + a;
        float2 v = outiv[i];
        out_idx[i] = v.x;
        out_val[i] = v.y;
    }
}

extern "C" void kernel_launch(void* const* d_in, const int* in_sizes, int n_in,
                              void* d_out, int out_size, void* d_ws, size_t ws_size,
                              hipStream_t stream) {
    const float* gt = (const float*)d_in[0];
    const float* anchors = (const float*)d_in[1];
    const int BG = in_sizes[0] / 4;   // B*G = 512
    const int B = BG / G;             // 8
    const int A = in_sizes[1] / 4;    // 120000

    const int nchunks = (A + 1023) / 1024;
    const int NB = (A + 255) / 256;   // sort-kernel blocks

    // ws layout (u32 units):
    // [0,512) hpg | [512,1024) gab | [1024,1280) cellTot |
    // [1280, +NB*256) bh | (align4) sortedA 4A | orig A |
    // sredg nchunks*B*64 | (align2) outiv 2*B*A | amaxS B*A
    unsigned int* ws = (unsigned int*)d_ws;
    unsigned int* hpg = ws;
    float* gab = (float*)(ws + 512);
    unsigned int* cellTot = ws + 1024;
    unsigned int* bh = ws + 1280;
    size_t soff = 1280 + (size_t)NB * 256;
    soff = (soff + 3) & ~(size_t)3;                 // 16B align for float4
    float* sortedA = (float*)(ws + soff);
    int* orig = (int*)(ws + soff + 4 * (size_t)A);
    unsigned int* sredg = ws + soff + 5 * (size_t)A;
    size_t ooff = soff + 5 * (size_t)A + (size_t)nchunks * B * G;
    ooff = (ooff + 1) & ~(size_t)1;                 // 8B align for float2
    float2* outiv = (float2*)(ws + ooff);
    int* amaxS = (int*)(ws + ooff + 2 * (size_t)B * A);
    const size_t need = (ooff + 3 * (size_t)B * A) * 4;
    const bool sorted = (ws_size >= need);

    float* out_idx = (float*)d_out;
    float* out_val = out_idx + (size_t)B * A;

    dim3 g1(nchunks, B);
    if (sorted) {
        k_count<<<NB, 256, 0, stream>>>(gt, anchors, bh, hpg, gab, A, NB, BG);
        k_rowscan<<<NCELL, 256, 0, stream>>>(bh, cellTot, NB);
        k_scat<<<NB, 256, 0, stream>>>(anchors, bh, cellTot, sortedA, orig, A, NB);
        pass1_k<true><<<g1, 256, 0, stream>>>(gt, sortedA, gab, hpg, sredg,
                                              amaxS, orig, outiv, A, nchunks);
        k_patch<true><<<g1, 256, 0, stream>>>(gt, sortedA, gab, hpg, sredg,
                                              amaxS, orig, outiv, A, nchunks);
        k_emit<<<g1, 256, 0, stream>>>(outiv, out_idx, out_val, A);
    } else {
        // Fallback: unsorted identity order (init via k_count; hist unused).
        k_count<<<NB, 256, 0, stream>>>(gt, anchors, bh, hpg, gab, A, NB, BG);
        pass1_k<false><<<g1, 256, 0, stream>>>(gt, anchors, gab, hpg, sredg,
                                               amaxS, orig, outiv, A, nchunks);
        k_patch<false><<<g1, 256, 0, stream>>>(gt, anchors, gab, hpg, sredg,
                                               amaxS, orig, outiv, A, nchunks);
        k_emit<<<g1, 256, 0, stream>>>(outiv, out_idx, out_val, A);
    }
}